// Round 2
// baseline (31167.258 us; speedup 1.0000x reference)
//
#include <hip/hip_runtime.h>
#include <math.h>

// Problem constants (match reference)
#define B_    64
#define T_    2048
#define DIN   256
#define DH    256
#define DC    256
#define DOUT  256
#define NG    4      // column-groups (WGs) per batch
#define COLS  64     // c/h/out columns owned per WG

__device__ __forceinline__ float sigmoidf_(float x) {
    return 1.0f / (1.0f + __expf(-x));
}

__device__ __forceinline__ float tanhf_(float x) {
    float ax = fabsf(x);
    float e  = __expf(-2.0f * ax);
    float t  = (1.0f - e) / (1.0f + e);
    return copysignf(t, x);
}

// 256 WGs = 64 batches x 4 column-groups. Each WG owns 64 columns of the
// f/i/o gates and of c/h/out. Per-timestep weight traffic per CU drops 4x
// vs the 1-WG-per-batch version (the measured 56 B/cyc per-CU load-path
// ceiling was the bottleneck). h is exchanged through a double-buffered
// global buffer with a per-batch monotonic flag (device-scope release/
// acquire). The x-half of the gate GEMV is computed BEFORE the wait (no h
// dependence) to hide handshake latency; Wout projection of step t-1 runs
// right after h_t is acquired.
__global__ __launch_bounds__(256) void lstm_colsplit(
    const float* __restrict__ x,    const float* __restrict__ h0,
    const float* __restrict__ c0,   const float* __restrict__ Wf,
    const float* __restrict__ bf,   const float* __restrict__ Wi,
    const float* __restrict__ bi,   const float* __restrict__ Wo,
    const float* __restrict__ bo,   const float* __restrict__ Wout,
    const float* __restrict__ bout, const int* __restrict__ Np,
    float* __restrict__ out,
    unsigned int* __restrict__ flags, float* __restrict__ hbuf)
{
    // wgid -> (b, g) such that all 4 WGs of a batch share wg%8 (same XCD
    // under round-robin dispatch -> L2-local handshake; heuristic only).
    const int wg  = blockIdx.x;
    const int xcd = wg & 7;
    const int j   = wg >> 3;           // 0..31
    const int b   = xcd + ((j & 7) << 3);
    const int g   = j >> 3;            // 0..3
    const int tid = threadIdx.x;
    const int ks  = tid >> 4;          // k-slice 0..15 (16 k each per half)
    const int c4  = (tid & 15) << 2;   // float4 column offset within slice
    const int C0  = g * COLS;
    const int N   = *Np;

    __shared__ float combX[DIN];
    __shared__ float combH[DH];
    __shared__ __align__(16) float part[3][16][COLS];   // 12 KiB partials

    unsigned int* flag = flags + b * 16;        // own 64B line per batch
    float* hb = hbuf + (size_t)b * (2 * DH);    // double-buffered h

    float c_st = 0.f, h_st = 0.f, bfv = 0.f, biv = 0.f, bov = 0.f, boutv = 0.f;
    if (tid < COLS) {
        c_st  = c0[b * DC + C0 + tid];
        bfv   = bf[C0 + tid];
        biv   = bi[C0 + tid];
        bov   = bo[C0 + tid];
        boutv = bout[C0 + tid];
    }
    combH[tid] = h0[b * DH + tid];
    __syncthreads();
    if (tid < COLS) h_st = combH[C0 + tid];

    const size_t xbase = (size_t)b * T_ * DIN;
    const float* Wfp = Wf + C0;
    const float* Wip = Wi + C0;
    const float* Wop = Wo + C0;
    const float* Wqp = Wout + C0;
    const int k0 = ks * 16;

    for (int t = 0; t < N; ++t) {
        combX[tid] = x[xbase + (size_t)t * DIN + tid];
        __syncthreads();

        // ---- x-half of gate GEMV (k in [0,256)) — independent of h_t ----
        float4 af = {0,0,0,0}, ai = {0,0,0,0}, ao = {0,0,0,0};
        #pragma unroll 4
        for (int kk = 0; kk < 16; ++kk) {
            const int k = k0 + kk;
            const float ck = combX[k];
            const float4 wf = *(const float4*)(Wfp + (size_t)k * DC + c4);
            const float4 wi = *(const float4*)(Wip + (size_t)k * DC + c4);
            const float4 wo = *(const float4*)(Wop + (size_t)k * DC + c4);
            af.x += ck*wf.x; af.y += ck*wf.y; af.z += ck*wf.z; af.w += ck*wf.w;
            ai.x += ck*wi.x; ai.y += ck*wi.y; ai.z += ck*wi.z; ai.w += ck*wi.w;
            ao.x += ck*wo.x; ao.y += ck*wo.y; ao.z += ck*wo.z; ao.w += ck*wo.w;
        }

        if (t > 0) {
            // ---- acquire h_t from the 4 column-groups of this batch ----
            if (tid == 0) {
                const unsigned int tgt = 4u * (unsigned int)t;
                while (__hip_atomic_load(flag, __ATOMIC_RELAXED,
                                         __HIP_MEMORY_SCOPE_AGENT) < tgt) {}
            }
            __syncthreads();
            __builtin_amdgcn_fence(__ATOMIC_ACQUIRE, "agent");
            combH[tid] = hb[((t & 1) * DH) + tid];
            __syncthreads();

            // ---- deferred output projection: out_{t-1} = sig(h_t @ Wout) ----
            float4 aq = {0,0,0,0};
            #pragma unroll 4
            for (int kk = 0; kk < 16; ++kk) {
                const int k = k0 + kk;
                const float hk = combH[k];
                const float4 w = *(const float4*)(Wqp + (size_t)k * DOUT + c4);
                aq.x += hk*w.x; aq.y += hk*w.y; aq.z += hk*w.z; aq.w += hk*w.w;
            }
            *(float4*)&part[0][ks][c4] = aq;
            __syncthreads();
            if (tid < COLS) {
                float q = boutv;
                #pragma unroll
                for (int s = 0; s < 16; ++s) q += part[0][s][tid];
                out[((size_t)b * N + (t - 1)) * DOUT + C0 + tid] = sigmoidf_(q);
            }
            __syncthreads();
        }
        // (t == 0: combH already holds h0)

        // ---- h-half of gate GEMV (k in [256,512)) ----
        #pragma unroll 4
        for (int kk = 0; kk < 16; ++kk) {
            const int k = k0 + kk;
            const float ck = combH[k];
            const float4 wf = *(const float4*)(Wfp + (size_t)(DIN + k) * DC + c4);
            const float4 wi = *(const float4*)(Wip + (size_t)(DIN + k) * DC + c4);
            const float4 wo = *(const float4*)(Wop + (size_t)(DIN + k) * DC + c4);
            af.x += ck*wf.x; af.y += ck*wf.y; af.z += ck*wf.z; af.w += ck*wf.w;
            ai.x += ck*wi.x; ai.y += ck*wi.y; ai.z += ck*wi.z; ai.w += ck*wi.w;
            ao.x += ck*wo.x; ao.y += ck*wo.y; ao.z += ck*wo.z; ao.w += ck*wo.w;
        }
        *(float4*)&part[0][ks][c4] = af;
        *(float4*)&part[1][ks][c4] = ai;
        *(float4*)&part[2][ks][c4] = ao;
        __syncthreads();

        // ---- gate math + state update (thread tid<64 owns column C0+tid) ----
        if (tid < COLS) {
            float fp = bfv, ip = biv, op = bov;
            #pragma unroll
            for (int s = 0; s < 16; ++s) {
                fp += part[0][s][tid];
                ip += part[1][s][tid];
                op += part[2][s][tid];
            }
            const float f = sigmoidf_(fp);
            const float i = sigmoidf_(ip);
            const float z = tanhf_(ip);      // pre_i reused for tanh per ref
            const float o = sigmoidf_(op);
            c_st = c_st * f + z * i;
            h_st = tanhf_(c_st) * o;
            hb[(((t + 1) & 1) * DH) + C0 + tid] = h_st;   // publish h_{t+1} chunk
        }
        __syncthreads();   // all lanes reach here; then release + bump flag
        if (tid == 0) {
            __builtin_amdgcn_fence(__ATOMIC_RELEASE, "agent");
            __hip_atomic_fetch_add(flag, 1u, __ATOMIC_RELAXED,
                                   __HIP_MEMORY_SCOPE_AGENT);
        }
    }

    // ---- epilogue: out_{N-1} needs h_N; then finals ----
    if (tid == 0) {
        const unsigned int tgt = 4u * (unsigned int)N;
        while (__hip_atomic_load(flag, __ATOMIC_RELAXED,
                                 __HIP_MEMORY_SCOPE_AGENT) < tgt) {}
    }
    __syncthreads();
    __builtin_amdgcn_fence(__ATOMIC_ACQUIRE, "agent");
    combH[tid] = hb[((N & 1) * DH) + tid];
    __syncthreads();

    float4 aq = {0,0,0,0};
    #pragma unroll 4
    for (int kk = 0; kk < 16; ++kk) {
        const int k = k0 + kk;
        const float hk = combH[k];
        const float4 w = *(const float4*)(Wqp + (size_t)k * DOUT + c4);
        aq.x += hk*w.x; aq.y += hk*w.y; aq.z += hk*w.z; aq.w += hk*w.w;
    }
    *(float4*)&part[0][ks][c4] = aq;
    __syncthreads();
    if (tid < COLS) {
        float q = boutv;
        #pragma unroll
        for (int s = 0; s < 16; ++s) q += part[0][s][tid];
        out[((size_t)b * N + (N - 1)) * DOUT + C0 + tid] = sigmoidf_(q);
        // finals: d_out = [ outs (B*N*DOUT) | h_final (B*DH) | c_final (B*DC) ]
        float* hf = out + (size_t)B_ * N * DOUT;
        float* cf = hf + (size_t)B_ * DH;
        hf[b * DH + C0 + tid] = h_st;
        cf[b * DC + C0 + tid] = c_st;
    }
}

extern "C" void kernel_launch(void* const* d_in, const int* in_sizes, int n_in,
                              void* d_out, int out_size, void* d_ws, size_t ws_size,
                              hipStream_t stream) {
    const float* x    = (const float*)d_in[0];
    const float* h0   = (const float*)d_in[1];
    const float* c0   = (const float*)d_in[2];
    const float* Wf   = (const float*)d_in[3];
    const float* bf   = (const float*)d_in[4];
    const float* Wi   = (const float*)d_in[5];
    const float* bi   = (const float*)d_in[6];
    const float* Wo   = (const float*)d_in[7];
    const float* bo   = (const float*)d_in[8];
    const float* Wout = (const float*)d_in[9];
    const float* bout = (const float*)d_in[10];
    const int*   Np   = (const int*)d_in[11];
    float* out = (float*)d_out;

    // workspace: [0,4KB) per-batch flag lines (zeroed each launch),
    //            [4KB, 4KB+128KB) double-buffered h exchange
    unsigned int* flags = (unsigned int*)d_ws;
    float* hbuf = (float*)((char*)d_ws + 4096);
    (void)hipMemsetAsync(d_ws, 0, 4096, stream);

    void* args[] = {
        (void*)&x,  (void*)&h0, (void*)&c0, (void*)&Wf,   (void*)&bf,
        (void*)&Wi, (void*)&bi, (void*)&Wo, (void*)&bo,   (void*)&Wout,
        (void*)&bout, (void*)&Np, (void*)&out, (void*)&flags, (void*)&hbuf
    };
    // cooperative launch guarantees all 256 WGs co-resident (spin safety)
    (void)hipLaunchCooperativeKernel((const void*)lstm_colsplit, dim3(NG * B_),
                                     dim3(256), args, 0, stream);
}

// Round 3
// 18000.366 us; speedup vs baseline: 1.7315x; 1.7315x over previous
//
#include <hip/hip_runtime.h>
#include <math.h>

// Problem constants (match reference)
#define B_    64
#define T_    2048
#define DIN   256
#define DH    256
#define DC    256
#define DOUT  256
#define K2    512   // DIN + DH

__device__ __forceinline__ float sigmoidf_(float x) {
    return 1.0f / (1.0f + __expf(-x));
}

__device__ __forceinline__ float tanhf_(float x) {
    float ax = fabsf(x);
    float e  = __expf(-2.0f * ax);
    float t  = (1.0f - e) / (1.0f + e);
    return copysignf(t, x);
}

// ---------------------------------------------------------------------------
// Phase 1: P[b,t,g*256+n] = x[b,t,:] @ Wg[0:256,:] + bg   (no recurrence)
// Grid: (M/32, 3 gates). 32-row M-tile in LDS, W streamed from L2 with 32-row
// reuse, each thread computes 8 rows x 4 cols. ~51.5 GFLOP fp32 on 256 CUs.
// ---------------------------------------------------------------------------
__global__ __launch_bounds__(256) void xgemm(
    const float* __restrict__ x,
    const float* __restrict__ Wf, const float* __restrict__ bf,
    const float* __restrict__ Wi, const float* __restrict__ bi,
    const float* __restrict__ Wo, const float* __restrict__ bo,
    float* __restrict__ P)
{
    const int mt  = blockIdx.x;          // 32-row tile index (0..4095)
    const int g   = blockIdx.y;          // gate 0..2
    const float* W    = (g == 0) ? Wf : (g == 1) ? Wi : Wo;
    const float* bias = (g == 0) ? bf : (g == 1) ? bi : bo;
    const int tid  = threadIdx.x;
    const int lane = tid & 63;
    const int rg   = tid >> 6;           // wave id -> row group rg*8..rg*8+7
    const int c4   = lane * 4;

    __shared__ __align__(16) float Xs[32][256];   // 32 KiB

    const size_t m0 = (size_t)mt * 32;
    #pragma unroll
    for (int j = 0; j < 8; ++j) {
        const int f4 = tid + j * 256;    // 0..2047 float4 slots
        const int r  = f4 >> 6;
        const int k4 = (f4 & 63) * 4;
        *(float4*)&Xs[r][k4] = *(const float4*)(x + (m0 + r) * DIN + k4);
    }
    __syncthreads();

    float4 acc[8];
    const float4 bz = *(const float4*)(bias + c4);
    #pragma unroll
    for (int r = 0; r < 8; ++r) acc[r] = bz;

    #pragma unroll 4
    for (int k = 0; k < 256; ++k) {
        const float4 wv = *(const float4*)(W + (size_t)k * DC + c4);
        #pragma unroll
        for (int r = 0; r < 8; ++r) {
            const float xv = Xs[rg * 8 + r][k];   // wave-uniform broadcast
            acc[r].x += xv * wv.x; acc[r].y += xv * wv.y;
            acc[r].z += xv * wv.z; acc[r].w += xv * wv.w;
        }
    }
    #pragma unroll
    for (int r = 0; r < 8; ++r) {
        *(float4*)(P + (m0 + rg * 8 + r) * 768 + (size_t)g * 256 + c4) = acc[r];
    }
}

// ---------------------------------------------------------------------------
// Phase 2: recurrence, 1 WG per batch (cross-WG per-step sync measured at
// ~12 us/step -> categorically excluded). Per-step load path is now only the
// h-half of the gate weights (786 KB) + Wout (262 KB) + P row (3 KB): ~1.05 MB
// vs 1.83 MB before -> predicted ~7.8 us/step at the measured 56 B/cyc
// per-CU L2 load ceiling.
// ---------------------------------------------------------------------------
__global__ __launch_bounds__(256) void lstm_rec(
    const float* __restrict__ P,    const float* __restrict__ h0,
    const float* __restrict__ c0,   const float* __restrict__ Wf,
    const float* __restrict__ Wi,   const float* __restrict__ Wo,
    const float* __restrict__ Wout, const float* __restrict__ bout,
    const int* __restrict__ Np,     float* __restrict__ out)
{
    const int b   = blockIdx.x;
    const int tid = threadIdx.x;
    const int sl  = tid >> 6;         // k-slice 0..3 (64 k each)
    const int cg  = (tid & 63) * 4;   // 4 adjacent output columns
    const int N   = *Np;

    __shared__ float combH[DH];
    __shared__ __align__(16) float part[3][4][DC];   // 12 KiB

    float c     = c0[b * DC + tid];
    float h_reg = h0[b * DH + tid];
    const float boutv = bout[tid];
    combH[tid] = h_reg;
    __syncthreads();

    // h-halves of the gate weights: rows 256..511
    const float* Wfh = Wf + (size_t)DIN * DC;
    const float* Wih = Wi + (size_t)DIN * DC;
    const float* Woh = Wo + (size_t)DIN * DC;
    const size_t pbase = (size_t)b * T_ * 768;
    const int k0 = sl * 64;

    for (int t = 0; t < N; ++t) {
        // pre-activation row (x-part + bias), prefetched; used after the GEMV
        const size_t pr = pbase + (size_t)t * 768 + tid;
        const float pf = P[pr];
        const float pi = P[pr + 256];
        const float po = P[pr + 512];

        // ---- gate h-GEMV: K=256 over 4 slices of 64 ----
        float4 af = {0,0,0,0}, ai = {0,0,0,0}, ao = {0,0,0,0};
        #pragma unroll 4
        for (int k = k0; k < k0 + 64; ++k) {
            const float ck = combH[k];   // wave-uniform LDS broadcast
            const float4 wf = *(const float4*)(Wfh + (size_t)k * DC + cg);
            const float4 wi = *(const float4*)(Wih + (size_t)k * DC + cg);
            const float4 wo = *(const float4*)(Woh + (size_t)k * DC + cg);
            af.x += ck*wf.x; af.y += ck*wf.y; af.z += ck*wf.z; af.w += ck*wf.w;
            ai.x += ck*wi.x; ai.y += ck*wi.y; ai.z += ck*wi.z; ai.w += ck*wi.w;
            ao.x += ck*wo.x; ao.y += ck*wo.y; ao.z += ck*wo.z; ao.w += ck*wo.w;
        }
        *(float4*)&part[0][sl][cg] = af;
        *(float4*)&part[1][sl][cg] = ai;
        *(float4*)&part[2][sl][cg] = ao;
        __syncthreads();

        // ---- per-column gate math (thread tid owns column tid) ----
        const int n = tid;
        float fp = pf + part[0][0][n] + part[0][1][n] + part[0][2][n] + part[0][3][n];
        float ip = pi + part[1][0][n] + part[1][1][n] + part[1][2][n] + part[1][3][n];
        float op = po + part[2][0][n] + part[2][1][n] + part[2][2][n] + part[2][3][n];
        const float f = sigmoidf_(fp);
        const float i = sigmoidf_(ip);
        const float z = tanhf_(ip);      // pre_i reused for tanh per reference
        const float o = sigmoidf_(op);
        c     = c * f + z * i;
        h_reg = tanhf_(c) * o;
        combH[n] = h_reg;                // publish h_{t+1}
        __syncthreads();

        // ---- output projection: out_t = sigmoid(h_{t+1} @ Wout + bout) ----
        float4 aq = {0,0,0,0};
        #pragma unroll 4
        for (int k = k0; k < k0 + 64; ++k) {
            const float hk = combH[k];
            const float4 w = *(const float4*)(Wout + (size_t)k * DOUT + cg);
            aq.x += hk*w.x; aq.y += hk*w.y; aq.z += hk*w.z; aq.w += hk*w.w;
        }
        *(float4*)&part[0][sl][cg] = aq;
        __syncthreads();
        const float q = boutv + part[0][0][n] + part[0][1][n]
                              + part[0][2][n] + part[0][3][n];
        out[((size_t)b * N + t) * DOUT + n] = sigmoidf_(q);
        __syncthreads();                 // protect part[] before next iteration
    }

    // finals: d_out = [ outs (B*N*DOUT) | h_final (B*DH) | c_final (B*DC) ]
    float* hf = out + (size_t)B_ * N * DOUT;
    float* cf = hf + (size_t)B_ * DH;
    hf[b * DH + tid] = h_reg;
    cf[b * DC + tid] = c;
}

// ---------------------------------------------------------------------------
// Fallback: round-0 kernel (proven 28 ms) if workspace is too small for P.
// ---------------------------------------------------------------------------
__global__ __launch_bounds__(256) void lstm_persistent(
    const float* __restrict__ x,    const float* __restrict__ h0,
    const float* __restrict__ c0,   const float* __restrict__ Wf,
    const float* __restrict__ bf,   const float* __restrict__ Wi,
    const float* __restrict__ bi,   const float* __restrict__ Wo,
    const float* __restrict__ bo,   const float* __restrict__ Wout,
    const float* __restrict__ bout, const int* __restrict__ Np,
    float* __restrict__ out)
{
    const int b   = blockIdx.x;
    const int tid = threadIdx.x;
    const int sl  = tid >> 6;
    const int cg  = (tid & 63) * 4;
    const int N   = *Np;

    __shared__ float comb[K2];
    __shared__ float part[3][4][DC];

    float c     = c0[b * DC + tid];
    float h_reg = h0[b * DH + tid];
    comb[DIN + tid] = h_reg;
    comb[tid]       = x[((size_t)b * T_ + 0) * DIN + tid];
    __syncthreads();

    const size_t xbase = (size_t)b * T_ * DIN;

    for (int t = 0; t < N; ++t) {
        float4 af = {0,0,0,0}, ai = {0,0,0,0}, ao = {0,0,0,0};
        const int k0 = sl * 128;
        #pragma unroll 4
        for (int k = k0; k < k0 + 128; ++k) {
            const float ck = comb[k];
            const float4 wf = *(const float4*)(Wf + (size_t)k * DC + cg);
            const float4 wi = *(const float4*)(Wi + (size_t)k * DC + cg);
            const float4 wo = *(const float4*)(Wo + (size_t)k * DC + cg);
            af.x += ck*wf.x; af.y += ck*wf.y; af.z += ck*wf.z; af.w += ck*wf.w;
            ai.x += ck*wi.x; ai.y += ck*wi.y; ai.z += ck*wi.z; ai.w += ck*wi.w;
            ao.x += ck*wo.x; ao.y += ck*wo.y; ao.z += ck*wo.z; ao.w += ck*wo.w;
        }
        *(float4*)&part[0][sl][cg] = af;
        *(float4*)&part[1][sl][cg] = ai;
        *(float4*)&part[2][sl][cg] = ao;
        __syncthreads();

        const int n = tid;
        float fp = bf[n] + part[0][0][n] + part[0][1][n] + part[0][2][n] + part[0][3][n];
        float ip = bi[n] + part[1][0][n] + part[1][1][n] + part[1][2][n] + part[1][3][n];
        float op = bo[n] + part[2][0][n] + part[2][1][n] + part[2][2][n] + part[2][3][n];
        const float f = sigmoidf_(fp);
        const float i = sigmoidf_(ip);
        const float z = tanhf_(ip);
        const float o = sigmoidf_(op);
        c     = c * f + z * i;
        h_reg = tanhf_(c) * o;
        __syncthreads();

        comb[DIN + n] = h_reg;
        if (t + 1 < N) comb[n] = x[xbase + (size_t)(t + 1) * DIN + n];
        __syncthreads();

        float4 aq = {0,0,0,0};
        const int q0 = sl * 64;
        #pragma unroll 4
        for (int k = q0; k < q0 + 64; ++k) {
            const float hk = comb[DIN + k];
            const float4 w = *(const float4*)(Wout + (size_t)k * DOUT + cg);
            aq.x += hk*w.x; aq.y += hk*w.y; aq.z += hk*w.z; aq.w += hk*w.w;
        }
        *(float4*)&part[0][sl][cg] = aq;
        __syncthreads();
        const float q = bout[n] + part[0][0][n] + part[0][1][n]
                                + part[0][2][n] + part[0][3][n];
        out[((size_t)b * N + t) * DOUT + n] = sigmoidf_(q);
        __syncthreads();
    }

    float* hf = out + (size_t)B_ * N * DOUT;
    float* cf = hf + (size_t)B_ * DH;
    hf[b * DH + tid] = h_reg;
    cf[b * DC + tid] = c;
}

extern "C" void kernel_launch(void* const* d_in, const int* in_sizes, int n_in,
                              void* d_out, int out_size, void* d_ws, size_t ws_size,
                              hipStream_t stream) {
    const float* x    = (const float*)d_in[0];
    const float* h0   = (const float*)d_in[1];
    const float* c0   = (const float*)d_in[2];
    const float* Wf   = (const float*)d_in[3];
    const float* bf   = (const float*)d_in[4];
    const float* Wi   = (const float*)d_in[5];
    const float* bi   = (const float*)d_in[6];
    const float* Wo   = (const float*)d_in[7];
    const float* bo   = (const float*)d_in[8];
    const float* Wout = (const float*)d_in[9];
    const float* bout = (const float*)d_in[10];
    const int*   Np   = (const int*)d_in[11];
    float* out = (float*)d_out;

    const size_t PSIZE = (size_t)B_ * T_ * 768 * sizeof(float);  // 403 MB
    if (ws_size >= PSIZE) {
        float* P = (float*)d_ws;
        hipLaunchKernelGGL(xgemm, dim3((B_ * T_) / 32, 3), dim3(256), 0, stream,
                           x, Wf, bf, Wi, bi, Wo, bo, P);
        hipLaunchKernelGGL(lstm_rec, dim3(B_), dim3(256), 0, stream,
                           P, h0, c0, Wf, Wi, Wo, Wout, bout, Np, out);
    } else {
        hipLaunchKernelGGL(lstm_persistent, dim3(B_), dim3(256), 0, stream,
                           x, h0, c0, Wf, bf, Wi, bi, Wo, bo, Wout, bout, Np, out);
    }
}

// Round 4
// 12405.520 us; speedup vs baseline: 2.5124x; 1.4510x over previous
//
#include <hip/hip_runtime.h>
#include <math.h>

// Problem constants (match reference)
#define B_    64
#define T_    2048
#define DIN   256
#define DH    256
#define DC    256
#define DOUT  256
#define K2    512   // DIN + DH
#define KS    9     // kk-iterations of the h-GEMV stashed in LDS (3 float4/thread each)

__device__ __forceinline__ float sigmoidf_(float x) {
    return 1.0f / (1.0f + __expf(-x));
}

__device__ __forceinline__ float tanhf_(float x) {
    float ax = fabsf(x);
    float e  = __expf(-2.0f * ax);
    float t  = (1.0f - e) / (1.0f + e);
    return copysignf(t, x);
}

// ---------------------------------------------------------------------------
// Phase 1: P[b,t,g*256+n] = x[b,t,:] @ Wg[0:256,:] + bg   (no recurrence)
// ---------------------------------------------------------------------------
__global__ __launch_bounds__(256) void xgemm(
    const float* __restrict__ x,
    const float* __restrict__ Wf, const float* __restrict__ bf,
    const float* __restrict__ Wi, const float* __restrict__ bi,
    const float* __restrict__ Wo, const float* __restrict__ bo,
    float* __restrict__ P)
{
    const int mt  = blockIdx.x;          // 32-row tile index
    const int g   = blockIdx.y;          // gate 0..2
    const float* W    = (g == 0) ? Wf : (g == 1) ? Wi : Wo;
    const float* bias = (g == 0) ? bf : (g == 1) ? bi : bo;
    const int tid  = threadIdx.x;
    const int lane = tid & 63;
    const int rg   = tid >> 6;           // wave id -> row group rg*8..rg*8+7
    const int c4   = lane * 4;

    __shared__ __align__(16) float Xs[32][256];   // 32 KiB

    const size_t m0 = (size_t)mt * 32;
    #pragma unroll
    for (int j = 0; j < 8; ++j) {
        const int f4 = tid + j * 256;
        const int r  = f4 >> 6;
        const int k4 = (f4 & 63) * 4;
        *(float4*)&Xs[r][k4] = *(const float4*)(x + (m0 + r) * DIN + k4);
    }
    __syncthreads();

    float4 acc[8];
    const float4 bz = *(const float4*)(bias + c4);
    #pragma unroll
    for (int r = 0; r < 8; ++r) acc[r] = bz;

    #pragma unroll 4
    for (int k = 0; k < 256; ++k) {
        const float4 wv = *(const float4*)(W + (size_t)k * DC + c4);
        #pragma unroll
        for (int r = 0; r < 8; ++r) {
            const float xv = Xs[rg * 8 + r][k];
            acc[r].x += xv * wv.x; acc[r].y += xv * wv.y;
            acc[r].z += xv * wv.z; acc[r].w += xv * wv.w;
        }
    }
    #pragma unroll
    for (int r = 0; r < 8; ++r) {
        *(float4*)(P + (m0 + rg * 8 + r) * 768 + (size_t)g * 256 + c4) = acc[r];
    }
}

// ---------------------------------------------------------------------------
// Phase 2: recurrence only (h,c). Writes RAW h_{t+1} into out[b,t,:]; the
// Wout projection is applied by outproj afterwards (it doesn't feed the
// recurrence, so it doesn't belong on the sequential critical path).
// Per-step streamed bytes: (55/64)*786KB gates + 3KB P row ~= 678 KB.
// KS=9 kk-rows of all 3 gate weights live in LDS (108 KB, lane-contiguous
// float4 layout -> conflict-free ds_read_b128, off the L1 critical path).
// ---------------------------------------------------------------------------
__global__ __launch_bounds__(256) void lstm_rec2(
    const float* __restrict__ P,    const float* __restrict__ h0,
    const float* __restrict__ c0,   const float* __restrict__ Wf,
    const float* __restrict__ Wi,   const float* __restrict__ Wo,
    const int* __restrict__ Np,     float* __restrict__ out)
{
    const int b   = blockIdx.x;
    const int tid = threadIdx.x;
    const int sl  = tid >> 6;         // k-slice 0..3 (64 k each)
    const int cg  = (tid & 63) * 4;   // 4 adjacent output columns
    const int N   = *Np;

    __shared__ float combH[DH];                       // 1 KiB
    __shared__ __align__(16) float part[3][4][DC];    // 12 KiB
    __shared__ __align__(16) float4 wst[KS * 3 * 256]; // 108 KiB stash

    float c     = c0[b * DC + tid];
    float h_reg = h0[b * DH + tid];
    combH[tid] = h_reg;

    // h-halves of the gate weights: rows 256..511
    const float* Wfh = Wf + (size_t)DIN * DC;
    const float* Wih = Wi + (size_t)DIN * DC;
    const float* Woh = Wo + (size_t)DIN * DC;
    const size_t pbase = (size_t)b * T_ * 768;
    const int k0 = sl * 64;

    // fill stash: first KS k-rows of this thread's slice, all 3 gates
    for (int kk = 0; kk < KS; ++kk) {
        wst[(kk * 3 + 0) * 256 + tid] = *(const float4*)(Wfh + (size_t)(k0 + kk) * DC + cg);
        wst[(kk * 3 + 1) * 256 + tid] = *(const float4*)(Wih + (size_t)(k0 + kk) * DC + cg);
        wst[(kk * 3 + 2) * 256 + tid] = *(const float4*)(Woh + (size_t)(k0 + kk) * DC + cg);
    }
    __syncthreads();

    for (int t = 0; t < N; ++t) {
        // pre-activation row (x-part + bias)
        const size_t pr = pbase + (size_t)t * 768 + tid;
        const float pf = P[pr];
        const float pi = P[pr + 256];
        const float po = P[pr + 512];

        float4 af = {0,0,0,0}, ai = {0,0,0,0}, ao = {0,0,0,0};

        // ---- LDS-stashed part of the h-GEMV ----
        #pragma unroll
        for (int kk = 0; kk < KS; ++kk) {
            const float ck = combH[k0 + kk];          // wave-uniform broadcast
            const float4 wf = wst[(kk * 3 + 0) * 256 + tid];
            const float4 wi = wst[(kk * 3 + 1) * 256 + tid];
            const float4 wo = wst[(kk * 3 + 2) * 256 + tid];
            af.x += ck*wf.x; af.y += ck*wf.y; af.z += ck*wf.z; af.w += ck*wf.w;
            ai.x += ck*wi.x; ai.y += ck*wi.y; ai.z += ck*wi.z; ai.w += ck*wi.w;
            ao.x += ck*wo.x; ao.y += ck*wo.y; ao.z += ck*wo.z; ao.w += ck*wo.w;
        }
        // ---- streamed part ----
        #pragma unroll 4
        for (int k = k0 + KS; k < k0 + 64; ++k) {
            const float ck = combH[k];
            const float4 wf = *(const float4*)(Wfh + (size_t)k * DC + cg);
            const float4 wi = *(const float4*)(Wih + (size_t)k * DC + cg);
            const float4 wo = *(const float4*)(Woh + (size_t)k * DC + cg);
            af.x += ck*wf.x; af.y += ck*wf.y; af.z += ck*wf.z; af.w += ck*wf.w;
            ai.x += ck*wi.x; ai.y += ck*wi.y; ai.z += ck*wi.z; ai.w += ck*wi.w;
            ao.x += ck*wo.x; ao.y += ck*wo.y; ao.z += ck*wo.z; ao.w += ck*wo.w;
        }
        *(float4*)&part[0][sl][cg] = af;
        *(float4*)&part[1][sl][cg] = ai;
        *(float4*)&part[2][sl][cg] = ao;
        __syncthreads();

        // ---- per-column gate math (thread tid owns column tid) ----
        const int n = tid;
        float fp = pf + part[0][0][n] + part[0][1][n] + part[0][2][n] + part[0][3][n];
        float ip = pi + part[1][0][n] + part[1][1][n] + part[1][2][n] + part[1][3][n];
        float op = po + part[2][0][n] + part[2][1][n] + part[2][2][n] + part[2][3][n];
        const float f = sigmoidf_(fp);
        const float i = sigmoidf_(ip);
        const float z = tanhf_(ip);      // pre_i reused for tanh per reference
        const float o = sigmoidf_(op);
        c     = c * f + z * i;
        h_reg = tanhf_(c) * o;
        combH[n] = h_reg;                            // publish h_{t+1}
        out[((size_t)b * N + t) * DOUT + n] = h_reg; // raw h; outproj fixes it up
        __syncthreads();                 // combH/part stable before next iter
    }

    // finals: d_out = [ outs (B*N*DOUT) | h_final (B*DH) | c_final (B*DC) ]
    float* hf = out + (size_t)B_ * N * DOUT;
    float* cf = hf + (size_t)B_ * DH;
    hf[b * DH + tid] = h_reg;
    cf[b * DC + tid] = c;
}

// ---------------------------------------------------------------------------
// Phase 3: in-place out[m,:] = sigmoid(out[m,:] @ Wout + bout) over m in
// [0, B*N). Each block owns 32 rows: reads them into LDS, then overwrites.
// Wout reused across 32 rows -> its loop-traffic cost amortizes 32x.
// ---------------------------------------------------------------------------
__global__ __launch_bounds__(256) void outproj(
    const float* __restrict__ Wout, const float* __restrict__ bout,
    const int* __restrict__ Np, float* __restrict__ out)
{
    const int N = *Np;
    const size_t m0 = (size_t)blockIdx.x * 32;
    if (m0 >= (size_t)B_ * N) return;    // B*N is a multiple of 32

    const int tid  = threadIdx.x;
    const int lane = tid & 63;
    const int rg   = tid >> 6;
    const int c4   = lane * 4;

    __shared__ __align__(16) float Hs[32][256];   // 32 KiB

    #pragma unroll
    for (int j = 0; j < 8; ++j) {
        const int f4 = tid + j * 256;
        const int r  = f4 >> 6;
        const int k4 = (f4 & 63) * 4;
        *(float4*)&Hs[r][k4] = *(const float4*)(out + (m0 + r) * DOUT + k4);
    }
    __syncthreads();

    float4 acc[8];
    const float4 bz = *(const float4*)(bout + c4);
    #pragma unroll
    for (int r = 0; r < 8; ++r) acc[r] = bz;

    #pragma unroll 4
    for (int k = 0; k < 256; ++k) {
        const float4 wv = *(const float4*)(Wout + (size_t)k * DOUT + c4);
        #pragma unroll
        for (int r = 0; r < 8; ++r) {
            const float hv = Hs[rg * 8 + r][k];
            acc[r].x += hv * wv.x; acc[r].y += hv * wv.y;
            acc[r].z += hv * wv.z; acc[r].w += hv * wv.w;
        }
    }
    #pragma unroll
    for (int r = 0; r < 8; ++r) {
        float4 q;
        q.x = sigmoidf_(acc[r].x); q.y = sigmoidf_(acc[r].y);
        q.z = sigmoidf_(acc[r].z); q.w = sigmoidf_(acc[r].w);
        *(float4*)(out + (m0 + rg * 8 + r) * DOUT + c4) = q;
    }
}

// ---------------------------------------------------------------------------
// Fallback: round-0 kernel (proven 28 ms) if workspace is too small for P.
// ---------------------------------------------------------------------------
__global__ __launch_bounds__(256) void lstm_persistent(
    const float* __restrict__ x,    const float* __restrict__ h0,
    const float* __restrict__ c0,   const float* __restrict__ Wf,
    const float* __restrict__ bf,   const float* __restrict__ Wi,
    const float* __restrict__ bi,   const float* __restrict__ Wo,
    const float* __restrict__ bo,   const float* __restrict__ Wout,
    const float* __restrict__ bout, const int* __restrict__ Np,
    float* __restrict__ out)
{
    const int b   = blockIdx.x;
    const int tid = threadIdx.x;
    const int sl  = tid >> 6;
    const int cg  = (tid & 63) * 4;
    const int N   = *Np;

    __shared__ float comb[K2];
    __shared__ float part[3][4][DC];

    float c     = c0[b * DC + tid];
    float h_reg = h0[b * DH + tid];
    comb[DIN + tid] = h_reg;
    comb[tid]       = x[((size_t)b * T_ + 0) * DIN + tid];
    __syncthreads();

    const size_t xbase = (size_t)b * T_ * DIN;

    for (int t = 0; t < N; ++t) {
        float4 af = {0,0,0,0}, ai = {0,0,0,0}, ao = {0,0,0,0};
        const int k0 = sl * 128;
        #pragma unroll 4
        for (int k = k0; k < k0 + 128; ++k) {
            const float ck = comb[k];
            const float4 wf = *(const float4*)(Wf + (size_t)k * DC + cg);
            const float4 wi = *(const float4*)(Wi + (size_t)k * DC + cg);
            const float4 wo = *(const float4*)(Wo + (size_t)k * DC + cg);
            af.x += ck*wf.x; af.y += ck*wf.y; af.z += ck*wf.z; af.w += ck*wf.w;
            ai.x += ck*wi.x; ai.y += ck*wi.y; ai.z += ck*wi.z; ai.w += ck*wi.w;
            ao.x += ck*wo.x; ao.y += ck*wo.y; ao.z += ck*wo.z; ao.w += ck*wo.w;
        }
        *(float4*)&part[0][sl][cg] = af;
        *(float4*)&part[1][sl][cg] = ai;
        *(float4*)&part[2][sl][cg] = ao;
        __syncthreads();

        const int n = tid;
        float fp = bf[n] + part[0][0][n] + part[0][1][n] + part[0][2][n] + part[0][3][n];
        float ip = bi[n] + part[1][0][n] + part[1][1][n] + part[1][2][n] + part[1][3][n];
        float op = bo[n] + part[2][0][n] + part[2][1][n] + part[2][2][n] + part[2][3][n];
        const float f = sigmoidf_(fp);
        const float i = sigmoidf_(ip);
        const float z = tanhf_(ip);
        const float o = sigmoidf_(op);
        c     = c * f + z * i;
        h_reg = tanhf_(c) * o;
        __syncthreads();

        comb[DIN + n] = h_reg;
        if (t + 1 < N) comb[n] = x[xbase + (size_t)(t + 1) * DIN + n];
        __syncthreads();

        float4 aq = {0,0,0,0};
        const int q0 = sl * 64;
        #pragma unroll 4
        for (int k = q0; k < q0 + 64; ++k) {
            const float hk = comb[DIN + k];
            const float4 w = *(const float4*)(Wout + (size_t)k * DOUT + cg);
            aq.x += hk*w.x; aq.y += hk*w.y; aq.z += hk*w.z; aq.w += hk*w.w;
        }
        *(float4*)&part[0][sl][cg] = aq;
        __syncthreads();
        const float q = bout[n] + part[0][0][n] + part[0][1][n]
                                + part[0][2][n] + part[0][3][n];
        out[((size_t)b * N + t) * DOUT + n] = sigmoidf_(q);
        __syncthreads();
    }

    float* hf = out + (size_t)B_ * N * DOUT;
    float* cf = hf + (size_t)B_ * DH;
    hf[b * DH + tid] = h_reg;
    cf[b * DC + tid] = c;
}

extern "C" void kernel_launch(void* const* d_in, const int* in_sizes, int n_in,
                              void* d_out, int out_size, void* d_ws, size_t ws_size,
                              hipStream_t stream) {
    const float* x    = (const float*)d_in[0];
    const float* h0   = (const float*)d_in[1];
    const float* c0   = (const float*)d_in[2];
    const float* Wf   = (const float*)d_in[3];
    const float* bf   = (const float*)d_in[4];
    const float* Wi   = (const float*)d_in[5];
    const float* bi   = (const float*)d_in[6];
    const float* Wo   = (const float*)d_in[7];
    const float* bo   = (const float*)d_in[8];
    const float* Wout = (const float*)d_in[9];
    const float* bout = (const float*)d_in[10];
    const int*   Np   = (const int*)d_in[11];
    float* out = (float*)d_out;

    const size_t PSIZE = (size_t)B_ * T_ * 768 * sizeof(float);  // 403 MB
    if (ws_size >= PSIZE) {
        float* P = (float*)d_ws;
        hipLaunchKernelGGL(xgemm, dim3((B_ * T_) / 32, 3), dim3(256), 0, stream,
                           x, Wf, bf, Wi, bi, Wo, bo, P);
        hipLaunchKernelGGL(lstm_rec2, dim3(B_), dim3(256), 0, stream,
                           P, h0, c0, Wf, Wi, Wo, Np, out);
        hipLaunchKernelGGL(outproj, dim3((B_ * T_) / 32), dim3(256), 0, stream,
                           Wout, bout, Np, out);
    } else {
        hipLaunchKernelGGL(lstm_persistent, dim3(B_), dim3(256), 0, stream,
                           x, h0, c0, Wf, bf, Wi, bi, Wo, bo, Wout, bout, Np, out);
    }
}

// Round 5
// 7047.540 us; speedup vs baseline: 4.4224x; 1.7603x over previous
//
#include <hip/hip_runtime.h>
#include <math.h>

// Problem constants (match reference)
#define B_    64
#define T_    2048
#define DIN   256
#define DH    256
#define DC    256
#define DOUT  256
#define K2    512   // DIN + DH
#define SPAIR 11    // k-pairs per slice stashed in LDS (of 32)

typedef _Float16 half2_t __attribute__((ext_vector_type(2)));

#if defined(__has_builtin)
#  if __has_builtin(__builtin_amdgcn_fdot2)
#    define FDOT2(a,b,c) __builtin_amdgcn_fdot2((a),(b),(c),false)
#  endif
#endif
#ifndef FDOT2   // scalar fallback if builtin unavailable
#  define FDOT2(a,b,c) ((c) + (float)(a)[0]*(float)(b)[0] + (float)(a)[1]*(float)(b)[1])
#endif

__device__ __forceinline__ float sigmoidf_(float x) {
    return 1.0f / (1.0f + __expf(-x));
}

__device__ __forceinline__ float tanhf_(float x) {
    float ax = fabsf(x);
    float e  = __expf(-2.0f * ax);
    float t  = (1.0f - e) / (1.0f + e);
    return copysignf(t, x);
}

// ---------------------------------------------------------------------------
// Phase 0: pack h-half gate weights to fp16 k-pairs.
// Wp[g][k2][n] = ( W[256+2k2][n], W[256+2k2+1][n] ) as half2. 393 KB total
// -> L2-resident for the whole recurrence.
// ---------------------------------------------------------------------------
__global__ __launch_bounds__(256) void packw(
    const float* __restrict__ Wf, const float* __restrict__ Wi,
    const float* __restrict__ Wo, half2_t* __restrict__ Wp)
{
    const int g     = blockIdx.x;        // gate 0..2
    const int chunk = blockIdx.y;        // 16 chunks x 8 k-pairs
    const int n     = threadIdx.x;
    const float* W = ((g == 0) ? Wf : (g == 1) ? Wi : Wo) + (size_t)DIN * DC;
    #pragma unroll
    for (int j = 0; j < 8; ++j) {
        const int k2 = chunk * 8 + j;
        half2_t p;
        p[0] = (_Float16)W[(size_t)(2 * k2)     * DC + n];
        p[1] = (_Float16)W[(size_t)(2 * k2 + 1) * DC + n];
        Wp[((size_t)g * 128 + k2) * 256 + n] = p;
    }
}

// ---------------------------------------------------------------------------
// Phase 1: P[b,t,g*256+n] = x[b,t,:] @ Wg[0:256,:] + bg   (no recurrence)
// ---------------------------------------------------------------------------
__global__ __launch_bounds__(256) void xgemm(
    const float* __restrict__ x,
    const float* __restrict__ Wf, const float* __restrict__ bf,
    const float* __restrict__ Wi, const float* __restrict__ bi,
    const float* __restrict__ Wo, const float* __restrict__ bo,
    float* __restrict__ P)
{
    const int mt  = blockIdx.x;
    const int g   = blockIdx.y;
    const float* W    = (g == 0) ? Wf : (g == 1) ? Wi : Wo;
    const float* bias = (g == 0) ? bf : (g == 1) ? bi : bo;
    const int tid  = threadIdx.x;
    const int lane = tid & 63;
    const int rg   = tid >> 6;
    const int c4   = lane * 4;

    __shared__ __align__(16) float Xs[32][256];

    const size_t m0 = (size_t)mt * 32;
    #pragma unroll
    for (int j = 0; j < 8; ++j) {
        const int f4 = tid + j * 256;
        const int r  = f4 >> 6;
        const int k4 = (f4 & 63) * 4;
        *(float4*)&Xs[r][k4] = *(const float4*)(x + (m0 + r) * DIN + k4);
    }
    __syncthreads();

    float4 acc[8];
    const float4 bz = *(const float4*)(bias + c4);
    #pragma unroll
    for (int r = 0; r < 8; ++r) acc[r] = bz;

    #pragma unroll 4
    for (int k = 0; k < 256; ++k) {
        const float4 wv = *(const float4*)(W + (size_t)k * DC + c4);
        #pragma unroll
        for (int r = 0; r < 8; ++r) {
            const float xv = Xs[rg * 8 + r][k];
            acc[r].x += xv * wv.x; acc[r].y += xv * wv.y;
            acc[r].z += xv * wv.z; acc[r].w += xv * wv.w;
        }
    }
    #pragma unroll
    for (int r = 0; r < 8; ++r) {
        *(float4*)(P + (m0 + rg * 8 + r) * 768 + (size_t)g * 256 + c4) = acc[r];
    }
}

// ---------------------------------------------------------------------------
// Phase 2: recurrence with fp16 h-GEMV (v_dot2_f32_f16, fp32 accumulate).
// Streamed bytes/step: (21/32)*393KB = 252 KB + 3 KB P row. SPAIR=11 k-pairs
// per slice live in LDS (132 KB). h is published to LDS as fp16 once/step.
// Writes RAW h into out[]; outproj applies Wout afterwards.
// ---------------------------------------------------------------------------
__global__ __launch_bounds__(256) void lstm_rec3(
    const float* __restrict__ P,    const float4* __restrict__ Wp4,
    const float* __restrict__ h0,   const float* __restrict__ c0,
    const int* __restrict__ Np,     float* __restrict__ out)
{
    const int b    = blockIdx.x;
    const int tid  = threadIdx.x;
    const int sl   = tid >> 6;        // k-slice 0..3 (32 k-pairs each)
    const int lane = tid & 63;
    const int cg   = lane * 4;        // 4 adjacent output columns
    const int N    = *Np;

    __shared__ _Float16 combHh[DH];                    // 512 B
    __shared__ __align__(16) float part[3][4][DC];     // 12 KiB
    __shared__ float4 wst[4 * SPAIR][3][64];           // 132 KiB stash

    float c     = c0[b * DC + tid];
    float h_reg = h0[b * DH + tid];
    combHh[tid] = (_Float16)h_reg;

    const int k0h = sl * 32;          // k-pair base of this slice

    // fill stash: first SPAIR k-pairs of this slice, all 3 gates
    for (int j = 0; j < SPAIR; ++j) {
        #pragma unroll
        for (int g = 0; g < 3; ++g)
            wst[sl * SPAIR + j][g][lane] =
                Wp4[((size_t)g * 128 + k0h + j) * 64 + lane];
    }
    __syncthreads();

    const size_t pbase = (size_t)b * T_ * 768;

    for (int t = 0; t < N; ++t) {
        // pre-activation row (x-part + bias), fp32
        const size_t pr = pbase + (size_t)t * 768 + tid;
        const float pf = P[pr];
        const float pi = P[pr + 256];
        const float po = P[pr + 512];

        float4 af = {0,0,0,0}, ai4 = {0,0,0,0}, ao4 = {0,0,0,0};

        // ---- LDS-stashed k-pairs ----
        #pragma unroll
        for (int j = 0; j < SPAIR; ++j) {
            const half2_t hk = *(const half2_t*)&combHh[(k0h + j) * 2];
            float4 rf = wst[sl * SPAIR + j][0][lane];
            float4 ri = wst[sl * SPAIR + j][1][lane];
            float4 ro = wst[sl * SPAIR + j][2][lane];
            const half2_t* wf = (const half2_t*)&rf;
            const half2_t* wi = (const half2_t*)&ri;
            const half2_t* wo = (const half2_t*)&ro;
            af.x  = FDOT2(wf[0], hk, af.x);  af.y  = FDOT2(wf[1], hk, af.y);
            af.z  = FDOT2(wf[2], hk, af.z);  af.w  = FDOT2(wf[3], hk, af.w);
            ai4.x = FDOT2(wi[0], hk, ai4.x); ai4.y = FDOT2(wi[1], hk, ai4.y);
            ai4.z = FDOT2(wi[2], hk, ai4.z); ai4.w = FDOT2(wi[3], hk, ai4.w);
            ao4.x = FDOT2(wo[0], hk, ao4.x); ao4.y = FDOT2(wo[1], hk, ao4.y);
            ao4.z = FDOT2(wo[2], hk, ao4.z); ao4.w = FDOT2(wo[3], hk, ao4.w);
        }
        // ---- streamed k-pairs (L2-resident fp16 weights) ----
        #pragma unroll 3
        for (int j = SPAIR; j < 32; ++j) {
            const half2_t hk = *(const half2_t*)&combHh[(k0h + j) * 2];
            float4 rf = Wp4[((size_t)0 * 128 + k0h + j) * 64 + lane];
            float4 ri = Wp4[((size_t)1 * 128 + k0h + j) * 64 + lane];
            float4 ro = Wp4[((size_t)2 * 128 + k0h + j) * 64 + lane];
            const half2_t* wf = (const half2_t*)&rf;
            const half2_t* wi = (const half2_t*)&ri;
            const half2_t* wo = (const half2_t*)&ro;
            af.x  = FDOT2(wf[0], hk, af.x);  af.y  = FDOT2(wf[1], hk, af.y);
            af.z  = FDOT2(wf[2], hk, af.z);  af.w  = FDOT2(wf[3], hk, af.w);
            ai4.x = FDOT2(wi[0], hk, ai4.x); ai4.y = FDOT2(wi[1], hk, ai4.y);
            ai4.z = FDOT2(wi[2], hk, ai4.z); ai4.w = FDOT2(wi[3], hk, ai4.w);
            ao4.x = FDOT2(wo[0], hk, ao4.x); ao4.y = FDOT2(wo[1], hk, ao4.y);
            ao4.z = FDOT2(wo[2], hk, ao4.z); ao4.w = FDOT2(wo[3], hk, ao4.w);
        }
        *(float4*)&part[0][sl][cg] = af;
        *(float4*)&part[1][sl][cg] = ai4;
        *(float4*)&part[2][sl][cg] = ao4;
        __syncthreads();

        // ---- per-column gate math (thread tid owns column tid) ----
        const int n = tid;
        float fp = pf + part[0][0][n] + part[0][1][n] + part[0][2][n] + part[0][3][n];
        float ip = pi + part[1][0][n] + part[1][1][n] + part[1][2][n] + part[1][3][n];
        float op = po + part[2][0][n] + part[2][1][n] + part[2][2][n] + part[2][3][n];
        const float f = sigmoidf_(fp);
        const float i = sigmoidf_(ip);
        const float z = tanhf_(ip);      // pre_i reused for tanh per reference
        const float o = sigmoidf_(op);
        c     = c * f + z * i;
        h_reg = tanhf_(c) * o;
        combHh[n] = (_Float16)h_reg;                 // publish h_{t+1} (fp16)
        out[((size_t)b * N + t) * DOUT + n] = h_reg; // raw h; outproj fixes up
        __syncthreads();                 // combHh/part stable before next iter
    }

    // finals: d_out = [ outs (B*N*DOUT) | h_final (B*DH) | c_final (B*DC) ]
    float* hf = out + (size_t)B_ * N * DOUT;
    float* cf = hf + (size_t)B_ * DH;
    hf[b * DH + tid] = h_reg;
    cf[b * DC + tid] = c;
}

// ---------------------------------------------------------------------------
// Phase 3: in-place out[m,:] = sigmoid(out[m,:] @ Wout + bout), 32 rows/block.
// ---------------------------------------------------------------------------
__global__ __launch_bounds__(256) void outproj(
    const float* __restrict__ Wout, const float* __restrict__ bout,
    const int* __restrict__ Np, float* __restrict__ out)
{
    const int N = *Np;
    const size_t m0 = (size_t)blockIdx.x * 32;
    if (m0 >= (size_t)B_ * N) return;

    const int tid  = threadIdx.x;
    const int lane = tid & 63;
    const int rg   = tid >> 6;
    const int c4   = lane * 4;

    __shared__ __align__(16) float Hs[32][256];

    #pragma unroll
    for (int j = 0; j < 8; ++j) {
        const int f4 = tid + j * 256;
        const int r  = f4 >> 6;
        const int k4 = (f4 & 63) * 4;
        *(float4*)&Hs[r][k4] = *(const float4*)(out + (m0 + r) * DOUT + k4);
    }
    __syncthreads();

    float4 acc[8];
    const float4 bz = *(const float4*)(bout + c4);
    #pragma unroll
    for (int r = 0; r < 8; ++r) acc[r] = bz;

    #pragma unroll 4
    for (int k = 0; k < 256; ++k) {
        const float4 wv = *(const float4*)(Wout + (size_t)k * DOUT + c4);
        #pragma unroll
        for (int r = 0; r < 8; ++r) {
            const float hv = Hs[rg * 8 + r][k];
            acc[r].x += hv * wv.x; acc[r].y += hv * wv.y;
            acc[r].z += hv * wv.z; acc[r].w += hv * wv.w;
        }
    }
    #pragma unroll
    for (int r = 0; r < 8; ++r) {
        float4 q;
        q.x = sigmoidf_(acc[r].x); q.y = sigmoidf_(acc[r].y);
        q.z = sigmoidf_(acc[r].z); q.w = sigmoidf_(acc[r].w);
        *(float4*)(out + (m0 + rg * 8 + r) * DOUT + c4) = q;
    }
}

// ---------------------------------------------------------------------------
// Fallback: round-0 kernel (proven 28 ms) if workspace is too small.
// ---------------------------------------------------------------------------
__global__ __launch_bounds__(256) void lstm_persistent(
    const float* __restrict__ x,    const float* __restrict__ h0,
    const float* __restrict__ c0,   const float* __restrict__ Wf,
    const float* __restrict__ bf,   const float* __restrict__ Wi,
    const float* __restrict__ bi,   const float* __restrict__ Wo,
    const float* __restrict__ bo,   const float* __restrict__ Wout,
    const float* __restrict__ bout, const int* __restrict__ Np,
    float* __restrict__ out)
{
    const int b   = blockIdx.x;
    const int tid = threadIdx.x;
    const int sl  = tid >> 6;
    const int cg  = (tid & 63) * 4;
    const int N   = *Np;

    __shared__ float comb[K2];
    __shared__ float part[3][4][DC];

    float c     = c0[b * DC + tid];
    float h_reg = h0[b * DH + tid];
    comb[DIN + tid] = h_reg;
    comb[tid]       = x[((size_t)b * T_ + 0) * DIN + tid];
    __syncthreads();

    const size_t xbase = (size_t)b * T_ * DIN;

    for (int t = 0; t < N; ++t) {
        float4 af = {0,0,0,0}, ai = {0,0,0,0}, ao = {0,0,0,0};
        const int k0 = sl * 128;
        #pragma unroll 4
        for (int k = k0; k < k0 + 128; ++k) {
            const float ck = comb[k];
            const float4 wf = *(const float4*)(Wf + (size_t)k * DC + cg);
            const float4 wi = *(const float4*)(Wi + (size_t)k * DC + cg);
            const float4 wo = *(const float4*)(Wo + (size_t)k * DC + cg);
            af.x += ck*wf.x; af.y += ck*wf.y; af.z += ck*wf.z; af.w += ck*wf.w;
            ai.x += ck*wi.x; ai.y += ck*wi.y; ai.z += ck*wi.z; ai.w += ck*wi.w;
            ao.x += ck*wo.x; ao.y += ck*wo.y; ao.z += ck*wo.z; ao.w += ck*wo.w;
        }
        *(float4*)&part[0][sl][cg] = af;
        *(float4*)&part[1][sl][cg] = ai;
        *(float4*)&part[2][sl][cg] = ao;
        __syncthreads();

        const int n = tid;
        float fp = bf[n] + part[0][0][n] + part[0][1][n] + part[0][2][n] + part[0][3][n];
        float ip = bi[n] + part[1][0][n] + part[1][1][n] + part[1][2][n] + part[1][3][n];
        float op = bo[n] + part[2][0][n] + part[2][1][n] + part[2][2][n] + part[2][3][n];
        const float f = sigmoidf_(fp);
        const float i = sigmoidf_(ip);
        const float z = tanhf_(ip);
        const float o = sigmoidf_(op);
        c     = c * f + z * i;
        h_reg = tanhf_(c) * o;
        __syncthreads();

        comb[DIN + n] = h_reg;
        if (t + 1 < N) comb[n] = x[xbase + (size_t)(t + 1) * DIN + n];
        __syncthreads();

        float4 aq = {0,0,0,0};
        const int q0 = sl * 64;
        #pragma unroll 4
        for (int k = q0; k < q0 + 64; ++k) {
            const float hk = comb[DIN + k];
            const float4 w = *(const float4*)(Wout + (size_t)k * DOUT + cg);
            aq.x += hk*w.x; aq.y += hk*w.y; aq.z += hk*w.z; aq.w += hk*w.w;
        }
        *(float4*)&part[0][sl][cg] = aq;
        __syncthreads();
        const float q = bout[n] + part[0][0][n] + part[0][1][n]
                                + part[0][2][n] + part[0][3][n];
        out[((size_t)b * N + t) * DOUT + n] = sigmoidf_(q);
        __syncthreads();
    }

    float* hf = out + (size_t)B_ * N * DOUT;
    float* cf = hf + (size_t)B_ * DH;
    hf[b * DH + tid] = h_reg;
    cf[b * DC + tid] = c;
}

extern "C" void kernel_launch(void* const* d_in, const int* in_sizes, int n_in,
                              void* d_out, int out_size, void* d_ws, size_t ws_size,
                              hipStream_t stream) {
    const float* x    = (const float*)d_in[0];
    const float* h0   = (const float*)d_in[1];
    const float* c0   = (const float*)d_in[2];
    const float* Wf   = (const float*)d_in[3];
    const float* bf   = (const float*)d_in[4];
    const float* Wi   = (const float*)d_in[5];
    const float* bi   = (const float*)d_in[6];
    const float* Wo   = (const float*)d_in[7];
    const float* bo   = (const float*)d_in[8];
    const float* Wout = (const float*)d_in[9];
    const float* bout = (const float*)d_in[10];
    const int*   Np   = (const int*)d_in[11];
    float* out = (float*)d_out;

    const size_t PSIZE  = (size_t)B_ * T_ * 768 * sizeof(float);   // 403 MB
    const size_t WPSIZE = (size_t)3 * 128 * 256 * 4;               // 393 KB
    if (ws_size >= PSIZE + WPSIZE) {
        float*   P  = (float*)d_ws;
        half2_t* Wp = (half2_t*)((char*)d_ws + PSIZE);
        hipLaunchKernelGGL(packw, dim3(3, 16), dim3(256), 0, stream,
                           Wf, Wi, Wo, Wp);
        hipLaunchKernelGGL(xgemm, dim3((B_ * T_) / 32, 3), dim3(256), 0, stream,
                           x, Wf, bf, Wi, bi, Wo, bo, P);
        hipLaunchKernelGGL(lstm_rec3, dim3(B_), dim3(256), 0, stream,
                           P, (const float4*)Wp, h0, c0, Np, out);
        hipLaunchKernelGGL(outproj, dim3((B_ * T_) / 32), dim3(256), 0, stream,
                           Wout, bout, Np, out);
    } else {
        hipLaunchKernelGGL(lstm_persistent, dim3(B_), dim3(256), 0, stream,
                           x, h0, c0, Wf, bf, Wi, bi, Wo, bo, Wout, bout, Np, out);
    }
}